// Round 4
// baseline (808.509 us; speedup 1.0000x reference)
//
#include <hip/hip_runtime.h>
#include <hip/hip_bf16.h>

#define HID 64
#define L 3

typedef unsigned short ushort_t;
typedef unsigned int uint_t;

static __device__ __forceinline__ ushort_t f2bf(float f) {
    uint_t u = __float_as_uint(f);
    uint_t r = (u + 0x7FFFu + ((u >> 16) & 1u)) >> 16;   // RNE
    return (ushort_t)r;
}
static __device__ __forceinline__ float bf2f(ushort_t u) {
    return __uint_as_float(((uint_t)u) << 16);
}

// ---------------- embed: h0 = h_in @ W + b  (+ optional bf16 mirror) ---------
__global__ __launch_bounds__(256) void k_embed(
    const float* __restrict__ in, const float* __restrict__ W,
    const float* __restrict__ bias, float* __restrict__ out,
    ushort_t* __restrict__ outbf, int N)
{
    __shared__ float xs[16][68];
    const int row16 = threadIdx.x >> 4;
    const int li    = threadIdx.x & 15;
    const int r     = blockIdx.x * 16 + row16;
    if (r >= N) return;
    float4 x4 = *(const float4*)(in + (size_t)r * 64 + 4 * li);
    xs[row16][4*li+0] = x4.x; xs[row16][4*li+1] = x4.y;
    xs[row16][4*li+2] = x4.z; xs[row16][4*li+3] = x4.w;
    float4 acc = *(const float4*)(bias + 4 * li);
#pragma unroll
    for (int k = 0; k < 64; k++) {
        float xk = xs[row16][k];
        float4 wv = *(const float4*)(W + k * 64 + 4 * li);
        acc.x += xk * wv.x; acc.y += xk * wv.y;
        acc.z += xk * wv.z; acc.w += xk * wv.w;
    }
    *(float4*)(out + (size_t)r * 64 + 4 * li) = acc;
    if (outbf) {
        ushort4 o;
        o.x = f2bf(acc.x); o.y = f2bf(acc.y); o.z = f2bf(acc.z); o.w = f2bf(acc.w);
        *(ushort4*)(outbf + (size_t)r * 64 + 4 * li) = o;
    }
}

// ---------------- A,B tables: A = h@WA + bA; B = h@WB (bf16 out) -------------
__global__ __launch_bounds__(256) void k_matmulAB(
    const float* __restrict__ h, const float* __restrict__ WA,
    const float* __restrict__ bA, const float* __restrict__ WB,
    ushort_t* __restrict__ A, ushort_t* __restrict__ B, int N)
{
    __shared__ float xs[16][68];
    const int row16 = threadIdx.x >> 4;
    const int li    = threadIdx.x & 15;
    const int r     = blockIdx.x * 16 + row16;
    if (r >= N) return;
    float4 x4 = *(const float4*)(h + (size_t)r * 64 + 4 * li);
    xs[row16][4*li+0] = x4.x; xs[row16][4*li+1] = x4.y;
    xs[row16][4*li+2] = x4.z; xs[row16][4*li+3] = x4.w;
    float4 accA = *(const float4*)(bA + 4 * li);
    float4 accB = make_float4(0.f, 0.f, 0.f, 0.f);
#pragma unroll
    for (int k = 0; k < 64; k++) {
        float xk = xs[row16][k];
        float4 wa = *(const float4*)(WA + k * 64 + 4 * li);
        float4 wb = *(const float4*)(WB + k * 64 + 4 * li);
        accA.x += xk * wa.x; accA.y += xk * wa.y;
        accA.z += xk * wa.z; accA.w += xk * wa.w;
        accB.x += xk * wb.x; accB.y += xk * wb.y;
        accB.z += xk * wb.z; accB.w += xk * wb.w;
    }
    ushort4 oa, ob;
    oa.x = f2bf(accA.x); oa.y = f2bf(accA.y); oa.z = f2bf(accA.z); oa.w = f2bf(accA.w);
    ob.x = f2bf(accB.x); ob.y = f2bf(accB.y); ob.z = f2bf(accB.z); ob.w = f2bf(accB.w);
    *(ushort4*)(A + (size_t)r * 64 + 4 * li) = oa;
    *(ushort4*)(B + (size_t)r * 64 + 4 * li) = ob;
}

// ---------------- CSR build ----------------
__global__ __launch_bounds__(256) void k_count(
    const int* __restrict__ dst, int* __restrict__ deg, int E)
{
    int e = blockIdx.x * 256 + threadIdx.x;
    if (e < E) atomicAdd(&deg[dst[e]], 1);
}

__global__ __launch_bounds__(1024) void k_scan(
    int* __restrict__ cursor, int* __restrict__ offsets, int N)
{
    __shared__ int wsum[16];
    __shared__ int carry_s;
    int tid = threadIdx.x, lane = tid & 63, wid = tid >> 6;
    if (tid == 0) carry_s = 0;
    __syncthreads();
    for (int base = 0; base < N; base += 1024) {
        int idx = base + tid;
        int v = (idx < N) ? cursor[idx] : 0;
        int x = v;
#pragma unroll
        for (int o = 1; o < 64; o <<= 1) {
            int t = __shfl_up(x, o, 64);
            if (lane >= o) x += t;
        }
        if (lane == 63) wsum[wid] = x;
        __syncthreads();
        if (wid == 0) {
            int s = (lane < 16) ? wsum[lane] : 0;
#pragma unroll
            for (int o = 1; o < 16; o <<= 1) {
                int t = __shfl_up(s, o, 64);
                if (lane >= o) s += t;
            }
            if (lane < 16) wsum[lane] = s;
        }
        __syncthreads();
        int woff  = (wid > 0) ? wsum[wid - 1] : 0;
        int carry = carry_s;
        int total = wsum[15];
        int excl  = carry + woff + x - v;
        if (idx < N) { offsets[idx] = excl; cursor[idx] = excl; }
        __syncthreads();
        if (tid == 0) carry_s = carry + total;
        __syncthreads();
        if (tid == 0 && base + 1024 >= N) offsets[N] = carry + total;
    }
}

// csr_se[pos] = {src, edge_id}, grouped by dst
__global__ __launch_bounds__(256) void k_fill(
    const int* __restrict__ src, const int* __restrict__ dst,
    int* __restrict__ cursor, int2* __restrict__ csr_se, int E)
{
    int e = blockIdx.x * 256 + threadIdx.x;
    if (e >= E) return;
    int pos = atomicAdd(&cursor[dst[e]], 1);
    csr_se[pos] = make_int2(src[e], e);
}

// ---------------- fused: edge-score head i (+ optional GIN layer i) ----------
// 16 lanes per dst node. Walk in-edges once:
//   score[eid] op= relu(A[s]+B[d]+e[eid]@Wc)·w2 + b2    (per-edge)
//   acc += h[s]                                          (aggregation, HASGIN)
// then GIN MLP + residual -> hout (+ bf16 mirror).
// MODE 0: score = ; 1: score += ; 2: score = relu(score + val)
template <int MODE, int HASGIN, int AGGBF>
__global__ __launch_bounds__(256) void k_fused(
    const float* __restrict__ h, float* __restrict__ hout,
    const ushort_t* __restrict__ hbf, ushort_t* __restrict__ hbfout,
    const ushort_t* __restrict__ A, const ushort_t* __restrict__ Bm,
    const float* __restrict__ ep,
    const int2* __restrict__ csr_se, const int* __restrict__ offsets,
    const float* __restrict__ Wc, const float* __restrict__ W2v,
    const float* __restrict__ b2p, float* __restrict__ score,
    const float* __restrict__ epsp,
    const float* __restrict__ W1, const float* __restrict__ b1,
    const float* __restrict__ s1, const float* __restrict__ sh1,
    const float* __restrict__ W2, const float* __restrict__ b2,
    const float* __restrict__ as_, const float* __restrict__ ash,
    const float* __restrict__ gs, const float* __restrict__ gsh, int N)
{
    __shared__ float xs[16][68];
    __shared__ float ts[16][68];
    const int row16 = threadIdx.x >> 4;
    const int li    = threadIdx.x & 15;
    const int r     = blockIdx.x * 16 + row16;
    if (r >= N) return;

    const float4 wc0 = *(const float4*)(Wc + li*4);
    const float4 wc1 = *(const float4*)(Wc + 64 + li*4);
    const float4 w2v = *(const float4*)(W2v + li*4);
    const float bb2 = b2p[0];
    ushort4 bu = *(const ushort4*)(Bm + (size_t)r * 64 + li*4);
    const float4 brow = make_float4(bf2f(bu.x), bf2f(bu.y), bf2f(bu.z), bf2f(bu.w));

    int beg = offsets[r], end = offsets[r + 1];
    float4 acc = make_float4(0.f, 0.f, 0.f, 0.f);

    int k = beg;
    for (; k + 1 < end; k += 2) {
        int2 se0 = csr_se[k];
        int2 se1 = csr_se[k + 1];
        ushort4 a0 = *(const ushort4*)(A + (size_t)se0.x * 64 + li*4);
        ushort4 a1 = *(const ushort4*)(A + (size_t)se1.x * 64 + li*4);
        float2 ev0 = *(const float2*)(ep + 2*(size_t)se0.y);
        float2 ev1 = *(const float2*)(ep + 2*(size_t)se1.y);
        if (HASGIN) {
            if (AGGBF) {
                ushort4 h0 = *(const ushort4*)(hbf + (size_t)se0.x * 64 + li*4);
                ushort4 h1 = *(const ushort4*)(hbf + (size_t)se1.x * 64 + li*4);
                acc.x += bf2f(h0.x) + bf2f(h1.x);
                acc.y += bf2f(h0.y) + bf2f(h1.y);
                acc.z += bf2f(h0.z) + bf2f(h1.z);
                acc.w += bf2f(h0.w) + bf2f(h1.w);
            } else {
                float4 h0 = *(const float4*)(h + (size_t)se0.x * 64 + li*4);
                float4 h1 = *(const float4*)(h + (size_t)se1.x * 64 + li*4);
                acc.x += h0.x + h1.x; acc.y += h0.y + h1.y;
                acc.z += h0.z + h1.z; acc.w += h0.w + h1.w;
            }
        }
        float z0 = bf2f(a0.x) + brow.x + ev0.x*wc0.x + ev0.y*wc1.x; z0 = z0 > 0.f ? z0 : 0.f;
        float z1 = bf2f(a0.y) + brow.y + ev0.x*wc0.y + ev0.y*wc1.y; z1 = z1 > 0.f ? z1 : 0.f;
        float z2 = bf2f(a0.z) + brow.z + ev0.x*wc0.z + ev0.y*wc1.z; z2 = z2 > 0.f ? z2 : 0.f;
        float z3 = bf2f(a0.w) + brow.w + ev0.x*wc0.w + ev0.y*wc1.w; z3 = z3 > 0.f ? z3 : 0.f;
        float p0 = z0*w2v.x + z1*w2v.y + z2*w2v.z + z3*w2v.w;
        z0 = bf2f(a1.x) + brow.x + ev1.x*wc0.x + ev1.y*wc1.x; z0 = z0 > 0.f ? z0 : 0.f;
        z1 = bf2f(a1.y) + brow.y + ev1.x*wc0.y + ev1.y*wc1.y; z1 = z1 > 0.f ? z1 : 0.f;
        z2 = bf2f(a1.z) + brow.z + ev1.x*wc0.z + ev1.y*wc1.z; z2 = z2 > 0.f ? z2 : 0.f;
        z3 = bf2f(a1.w) + brow.w + ev1.x*wc0.w + ev1.y*wc1.w; z3 = z3 > 0.f ? z3 : 0.f;
        float p1 = z0*w2v.x + z1*w2v.y + z2*w2v.z + z3*w2v.w;
        p0 += __shfl_xor(p0, 1); p1 += __shfl_xor(p1, 1);
        p0 += __shfl_xor(p0, 2); p1 += __shfl_xor(p1, 2);
        p0 += __shfl_xor(p0, 4); p1 += __shfl_xor(p1, 4);
        p0 += __shfl_xor(p0, 8); p1 += __shfl_xor(p1, 8);
        if (li == 0) {
            if (MODE == 0) {
                score[se0.y] = p0 + bb2;
                score[se1.y] = p1 + bb2;
            } else if (MODE == 1) {
                score[se0.y] += p0 + bb2;
                score[se1.y] += p1 + bb2;
            } else {
                float v0 = score[se0.y] + p0 + bb2;
                float v1 = score[se1.y] + p1 + bb2;
                score[se0.y] = v0 > 0.f ? v0 : 0.f;
                score[se1.y] = v1 > 0.f ? v1 : 0.f;
            }
        }
    }
    if (k < end) {
        int2 se0 = csr_se[k];
        ushort4 a0 = *(const ushort4*)(A + (size_t)se0.x * 64 + li*4);
        float2 ev0 = *(const float2*)(ep + 2*(size_t)se0.y);
        if (HASGIN) {
            if (AGGBF) {
                ushort4 h0 = *(const ushort4*)(hbf + (size_t)se0.x * 64 + li*4);
                acc.x += bf2f(h0.x); acc.y += bf2f(h0.y);
                acc.z += bf2f(h0.z); acc.w += bf2f(h0.w);
            } else {
                float4 h0 = *(const float4*)(h + (size_t)se0.x * 64 + li*4);
                acc.x += h0.x; acc.y += h0.y; acc.z += h0.z; acc.w += h0.w;
            }
        }
        float z0 = bf2f(a0.x) + brow.x + ev0.x*wc0.x + ev0.y*wc1.x; z0 = z0 > 0.f ? z0 : 0.f;
        float z1 = bf2f(a0.y) + brow.y + ev0.x*wc0.y + ev0.y*wc1.y; z1 = z1 > 0.f ? z1 : 0.f;
        float z2 = bf2f(a0.z) + brow.z + ev0.x*wc0.z + ev0.y*wc1.z; z2 = z2 > 0.f ? z2 : 0.f;
        float z3 = bf2f(a0.w) + brow.w + ev0.x*wc0.w + ev0.y*wc1.w; z3 = z3 > 0.f ? z3 : 0.f;
        float p0 = z0*w2v.x + z1*w2v.y + z2*w2v.z + z3*w2v.w;
        p0 += __shfl_xor(p0, 1);
        p0 += __shfl_xor(p0, 2);
        p0 += __shfl_xor(p0, 4);
        p0 += __shfl_xor(p0, 8);
        if (li == 0) {
            if (MODE == 0)      score[se0.y] = p0 + bb2;
            else if (MODE == 1) score[se0.y] += p0 + bb2;
            else {
                float v0 = score[se0.y] + p0 + bb2;
                score[se0.y] = v0 > 0.f ? v0 : 0.f;
            }
        }
    }

    if (!HASGIN) return;

    // --- GIN: x = (1+eps)h + acc; t = relu(bn1(x@W1+b1)); u = t@W2+b2;
    //          u = relu(bn_a(u)); u = relu(bn_g(u)); hout = h + u ---
    const float epsv = 1.0f + epsp[0];
    float4 hv = *(const float4*)(h + (size_t)r * 64 + 4 * li);
    xs[row16][4*li+0] = epsv * hv.x + acc.x;
    xs[row16][4*li+1] = epsv * hv.y + acc.y;
    xs[row16][4*li+2] = epsv * hv.z + acc.z;
    xs[row16][4*li+3] = epsv * hv.w + acc.w;

    float4 t = *(const float4*)(b1 + 4 * li);
#pragma unroll
    for (int kk = 0; kk < 64; kk++) {
        float xk = xs[row16][kk];
        float4 wv = *(const float4*)(W1 + kk * 64 + 4 * li);
        t.x += xk * wv.x; t.y += xk * wv.y; t.z += xk * wv.z; t.w += xk * wv.w;
    }
    {
        float4 sc = *(const float4*)(s1 + 4 * li);
        float4 sh = *(const float4*)(sh1 + 4 * li);
        t.x = t.x * sc.x + sh.x; t.x = t.x > 0.f ? t.x : 0.f;
        t.y = t.y * sc.y + sh.y; t.y = t.y > 0.f ? t.y : 0.f;
        t.z = t.z * sc.z + sh.z; t.z = t.z > 0.f ? t.z : 0.f;
        t.w = t.w * sc.w + sh.w; t.w = t.w > 0.f ? t.w : 0.f;
    }
    ts[row16][4*li+0] = t.x; ts[row16][4*li+1] = t.y;
    ts[row16][4*li+2] = t.z; ts[row16][4*li+3] = t.w;

    float4 u = *(const float4*)(b2 + 4 * li);
#pragma unroll
    for (int kk = 0; kk < 64; kk++) {
        float tk = ts[row16][kk];
        float4 wv = *(const float4*)(W2 + kk * 64 + 4 * li);
        u.x += tk * wv.x; u.y += tk * wv.y; u.z += tk * wv.z; u.w += tk * wv.w;
    }
    {
        float4 sc = *(const float4*)(as_ + 4 * li);
        float4 sh = *(const float4*)(ash + 4 * li);
        u.x = u.x * sc.x + sh.x; u.x = u.x > 0.f ? u.x : 0.f;
        u.y = u.y * sc.y + sh.y; u.y = u.y > 0.f ? u.y : 0.f;
        u.z = u.z * sc.z + sh.z; u.z = u.z > 0.f ? u.z : 0.f;
        u.w = u.w * sc.w + sh.w; u.w = u.w > 0.f ? u.w : 0.f;
        sc = *(const float4*)(gs + 4 * li);
        sh = *(const float4*)(gsh + 4 * li);
        u.x = u.x * sc.x + sh.x; u.x = u.x > 0.f ? u.x : 0.f;
        u.y = u.y * sc.y + sh.y; u.y = u.y > 0.f ? u.y : 0.f;
        u.z = u.z * sc.z + sh.z; u.z = u.z > 0.f ? u.z : 0.f;
        u.w = u.w * sc.w + sh.w; u.w = u.w > 0.f ? u.w : 0.f;
    }
    float4 o = make_float4(hv.x + u.x, hv.y + u.y, hv.z + u.z, hv.w + u.w);
    *(float4*)(hout + (size_t)r * 64 + 4 * li) = o;
    if (AGGBF) {
        ushort4 ob;
        ob.x = f2bf(o.x); ob.y = f2bf(o.y); ob.z = f2bf(o.z); ob.w = f2bf(o.w);
        *(ushort4*)(hbfout + (size_t)r * 64 + 4 * li) = ob;
    }
}

extern "C" void kernel_launch(void* const* d_in, const int* in_sizes, int n_in,
                              void* d_out, int out_size, void* d_ws, size_t ws_size,
                              hipStream_t stream) {
    const float* h_in  = (const float*)d_in[0];
    const float* e     = (const float*)d_in[1];
    const int*   src   = (const int*)d_in[2];
    const int*   dst   = (const int*)d_in[3];
    const float* emb_W = (const float*)d_in[4];
    const float* emb_b = (const float*)d_in[5];
    const float* eps   = (const float*)d_in[6];
    const float* mW1   = (const float*)d_in[7];
    const float* mb1   = (const float*)d_in[8];
    const float* mbs   = (const float*)d_in[9];
    const float* mbsh  = (const float*)d_in[10];
    const float* mW2   = (const float*)d_in[11];
    const float* mb2   = (const float*)d_in[12];
    const float* as_   = (const float*)d_in[13];
    const float* ash   = (const float*)d_in[14];
    const float* gs    = (const float*)d_in[15];
    const float* gsh   = (const float*)d_in[16];
    const float* pW1   = (const float*)d_in[17];
    const float* pb1   = (const float*)d_in[18];
    const float* pW2   = (const float*)d_in[19];
    const float* pb2   = (const float*)d_in[20];

    const int N = in_sizes[0] / 64;
    const int E = in_sizes[2];
    const size_t nrow = (size_t)N * 64;

    float* score = (float*)d_out;

    // layout: h0,h1 (fp32) | A,B (bf16) | csr_se (int2) | offsets | cursor | [hbf0,hbf1]
    char* wp = (char*)d_ws;
    float* h0 = (float*)wp;          wp += nrow * 4;
    float* h1 = (float*)wp;          wp += nrow * 4;
    ushort_t* Abuf = (ushort_t*)wp;  wp += nrow * 2;
    ushort_t* Bbuf = (ushort_t*)wp;  wp += nrow * 2;
    int2* csr_se = (int2*)wp;        wp += (size_t)E * 8;
    int* offsets = (int*)wp;         wp += (size_t)(N + 1) * 4;
    int* cursor  = (int*)wp;         wp += (size_t)N * 4;
    size_t base_need = (size_t)(wp - (char*)d_ws);
    ushort_t* hbf0 = (ushort_t*)wp;
    ushort_t* hbf1 = (ushort_t*)(wp + nrow * 2);
    const bool use_bf = ws_size >= base_need + 2 * nrow * 2;
    if (!use_bf) { hbf0 = nullptr; hbf1 = nullptr; }

    const int rowBlocks = (N + 15) / 16;
    const int edgeGrid  = (E + 255) / 256;

    // ---- CSR build (graph static; shared by all heads/layers) ----
    hipMemsetAsync(cursor, 0, (size_t)N * sizeof(int), stream);
    k_count<<<edgeGrid, 256, 0, stream>>>(dst, cursor, E);
    k_scan<<<1, 1024, 0, stream>>>(cursor, offsets, N);
    k_fill<<<edgeGrid, 256, 0, stream>>>(src, dst, cursor, csr_se, E);

    // h0 = h_in @ emb_W + emb_b (+ bf16 mirror)
    k_embed<<<rowBlocks, 256, 0, stream>>>(h_in, emb_W, emb_b, h0, hbf0, N);

    float* hcur = h0;     float* hnext = h1;
    ushort_t* bcur = hbf0; ushort_t* bnext = hbf1;

    for (int i = 0; i <= L; i++) {
        const float* pw = pW1 + (size_t)i * 130 * 64;
        k_matmulAB<<<rowBlocks, 256, 0, stream>>>(hcur, pw, pb1 + i*64, pw + 64*64,
                                                  Abuf, Bbuf, N);
        const float* Wc = pw + 128 * 64;
        const float* w2 = pW2 + (size_t)i * 64;
        const float* b2 = pb2 + i;

        if (i < L) {
            const float* gW1 = mW1 + (size_t)i*64*64;
            const float* gW2 = mW2 + (size_t)i*64*64;
            if (use_bf) {
                if (i == 0)
                    k_fused<0,1,1><<<rowBlocks, 256, 0, stream>>>(
                        hcur, hnext, bcur, bnext, Abuf, Bbuf, e, csr_se, offsets,
                        Wc, w2, b2, score, eps + i, gW1, mb1 + i*64, mbs + i*64,
                        mbsh + i*64, gW2, mb2 + i*64, as_ + i*64, ash + i*64,
                        gs + i*64, gsh + i*64, N);
                else
                    k_fused<1,1,1><<<rowBlocks, 256, 0, stream>>>(
                        hcur, hnext, bcur, bnext, Abuf, Bbuf, e, csr_se, offsets,
                        Wc, w2, b2, score, eps + i, gW1, mb1 + i*64, mbs + i*64,
                        mbsh + i*64, gW2, mb2 + i*64, as_ + i*64, ash + i*64,
                        gs + i*64, gsh + i*64, N);
            } else {
                if (i == 0)
                    k_fused<0,1,0><<<rowBlocks, 256, 0, stream>>>(
                        hcur, hnext, bcur, bnext, Abuf, Bbuf, e, csr_se, offsets,
                        Wc, w2, b2, score, eps + i, gW1, mb1 + i*64, mbs + i*64,
                        mbsh + i*64, gW2, mb2 + i*64, as_ + i*64, ash + i*64,
                        gs + i*64, gsh + i*64, N);
                else
                    k_fused<1,1,0><<<rowBlocks, 256, 0, stream>>>(
                        hcur, hnext, bcur, bnext, Abuf, Bbuf, e, csr_se, offsets,
                        Wc, w2, b2, score, eps + i, gW1, mb1 + i*64, mbs + i*64,
                        mbsh + i*64, gW2, mb2 + i*64, as_ + i*64, ash + i*64,
                        gs + i*64, gsh + i*64, N);
            }
            { float* t = hcur; hcur = hnext; hnext = t; }
            { ushort_t* t = bcur; bcur = bnext; bnext = t; }
        } else {
            // final head: score = relu(score + pred); no aggregation / GIN
            k_fused<2,0,0><<<rowBlocks, 256, 0, stream>>>(
                hcur, nullptr, nullptr, nullptr, Abuf, Bbuf, e, csr_se, offsets,
                Wc, w2, b2, score, nullptr, nullptr, nullptr, nullptr,
                nullptr, nullptr, nullptr, nullptr, nullptr, nullptr, nullptr, N);
        }
    }
}

// Round 5
// 616.440 us; speedup vs baseline: 1.3116x; 1.3116x over previous
//
#include <hip/hip_runtime.h>

typedef unsigned short ushort_t;
typedef unsigned int uint_t;

static __device__ __forceinline__ ushort_t f2bf(float f) {
    uint_t u = __float_as_uint(f);
    uint_t r = (u + 0x7FFFu + ((u >> 16) & 1u)) >> 16;   // RNE
    return (ushort_t)r;
}
static __device__ __forceinline__ float bf2f(ushort_t u) {
    return __uint_as_float(((uint_t)u) << 16);
}

static __device__ __forceinline__ float edge_p(
    ushort4 a, float4 brow, float ex, float ey,
    float4 wc0, float4 wc1, float4 w2v)
{
    float z0 = bf2f(a.x) + brow.x + ex*wc0.x + ey*wc1.x; z0 = fmaxf(z0, 0.f);
    float z1 = bf2f(a.y) + brow.y + ex*wc0.y + ey*wc1.y; z1 = fmaxf(z1, 0.f);
    float z2 = bf2f(a.z) + brow.z + ex*wc0.z + ey*wc1.z; z2 = fmaxf(z2, 0.f);
    float z3 = bf2f(a.w) + brow.w + ex*wc0.w + ey*wc1.w; z3 = fmaxf(z3, 0.f);
    return z0*w2v.x + z1*w2v.y + z2*w2v.z + z3*w2v.w;
}

#define RED16(p) { p += __shfl_xor(p,1); p += __shfl_xor(p,2); \
                   p += __shfl_xor(p,4); p += __shfl_xor(p,8); }

// ---------------- CSR build ----------------
__global__ __launch_bounds__(256) void k_count(
    const int* __restrict__ dst, int* __restrict__ deg, int E)
{
    int e = blockIdx.x * 256 + threadIdx.x;
    if (e < E) atomicAdd(&deg[dst[e]], 1);
}

// per-block (1024) exclusive scan: partial[idx], bsum[block]
__global__ __launch_bounds__(1024) void k_scanA(
    const int* __restrict__ deg, int* __restrict__ partial,
    int* __restrict__ bsum, int N)
{
    __shared__ int wsum[16];
    int tid = threadIdx.x, lane = tid & 63, wid = tid >> 6;
    int idx = blockIdx.x * 1024 + tid;
    int v = (idx < N) ? deg[idx] : 0;
    int x = v;
#pragma unroll
    for (int o = 1; o < 64; o <<= 1) {
        int t = __shfl_up(x, o, 64);
        if (lane >= o) x += t;
    }
    if (lane == 63) wsum[wid] = x;
    __syncthreads();
    if (wid == 0) {
        int s = (lane < 16) ? wsum[lane] : 0;
#pragma unroll
        for (int o = 1; o < 16; o <<= 1) {
            int t = __shfl_up(s, o, 64);
            if (lane >= o) s += t;
        }
        if (lane < 16) wsum[lane] = s;
    }
    __syncthreads();
    int woff = (wid > 0) ? wsum[wid - 1] : 0;
    if (idx < N) partial[idx] = woff + x - v;
    if (tid == 0) bsum[blockIdx.x] = wsum[15];
}

// single block: exclusive scan of nb block sums (nb <= 256), total -> *totalp
__global__ __launch_bounds__(256) void k_scanB(
    int* __restrict__ bsum, int nb, int* __restrict__ totalp)
{
    __shared__ int s[256];
    int tid = threadIdx.x;
    int v = (tid < nb) ? bsum[tid] : 0;
    s[tid] = v;
    __syncthreads();
#pragma unroll
    for (int off = 1; off < 256; off <<= 1) {
        int t = (tid >= off) ? s[tid - off] : 0;
        __syncthreads();
        s[tid] += t;
        __syncthreads();
    }
    if (tid < nb) bsum[tid] = s[tid] - v;     // exclusive
    if (tid == 0) totalp[0] = s[255];
}

__global__ __launch_bounds__(256) void k_scanC(
    int* __restrict__ offsets, const int* __restrict__ bsum,
    int* __restrict__ cursor, int N)
{
    int idx = blockIdx.x * 256 + threadIdx.x;
    if (idx >= N) return;
    int o = offsets[idx] + bsum[idx >> 10];
    offsets[idx] = o;
    cursor[idx] = o;
}

// entries[pos] = {src, eid, e.x, e.y}, grouped by dst
__global__ __launch_bounds__(256) void k_fill(
    const int* __restrict__ src, const int* __restrict__ dst,
    const float* __restrict__ ep, int* __restrict__ cursor,
    int4* __restrict__ entries, int E)
{
    int ei = blockIdx.x * 256 + threadIdx.x;
    if (ei >= E) return;
    int pos = atomicAdd(&cursor[dst[ei]], 1);
    float2 ev = *(const float2*)(ep + 2 * (size_t)ei);
    entries[pos] = make_int4(src[ei], ei, __float_as_int(ev.x), __float_as_int(ev.y));
}

// ------------- embed + head-0 A/B tables (epilogue-fused) -------------
__global__ __launch_bounds__(256) void k_embed_ab(
    const float* __restrict__ in, const float* __restrict__ W,
    const float* __restrict__ bias, float* __restrict__ hout,
    ushort_t* __restrict__ hbfout,
    const float* __restrict__ WA, const float* __restrict__ bA,
    const float* __restrict__ WB,
    ushort_t* __restrict__ A, ushort_t* __restrict__ B, int N)
{
    __shared__ float xs[16][68];
    const int row16 = threadIdx.x >> 4;
    const int li    = threadIdx.x & 15;
    const int r     = blockIdx.x * 16 + row16;
    if (r >= N) return;
    float4 x4 = *(const float4*)(in + (size_t)r * 64 + 4 * li);
    xs[row16][4*li+0] = x4.x; xs[row16][4*li+1] = x4.y;
    xs[row16][4*li+2] = x4.z; xs[row16][4*li+3] = x4.w;
    float4 acc = *(const float4*)(bias + 4 * li);
#pragma unroll
    for (int k = 0; k < 64; k++) {
        float xk = xs[row16][k];
        float4 wv = *(const float4*)(W + k * 64 + 4 * li);
        acc.x += xk * wv.x; acc.y += xk * wv.y;
        acc.z += xk * wv.z; acc.w += xk * wv.w;
    }
    *(float4*)(hout + (size_t)r * 64 + 4 * li) = acc;
    if (hbfout) {
        ushort4 o;
        o.x = f2bf(acc.x); o.y = f2bf(acc.y); o.z = f2bf(acc.z); o.w = f2bf(acc.w);
        *(ushort4*)(hbfout + (size_t)r * 64 + 4 * li) = o;
    }
    // restage h row (same wave -> no barrier needed)
    xs[row16][4*li+0] = acc.x; xs[row16][4*li+1] = acc.y;
    xs[row16][4*li+2] = acc.z; xs[row16][4*li+3] = acc.w;
    float4 aA = *(const float4*)(bA + 4 * li);
    float4 aB = make_float4(0.f, 0.f, 0.f, 0.f);
#pragma unroll
    for (int k = 0; k < 64; k++) {
        float xk = xs[row16][k];
        float4 wa = *(const float4*)(WA + k * 64 + 4 * li);
        float4 wb = *(const float4*)(WB + k * 64 + 4 * li);
        aA.x += xk * wa.x; aA.y += xk * wa.y; aA.z += xk * wa.z; aA.w += xk * wa.w;
        aB.x += xk * wb.x; aB.y += xk * wb.y; aB.z += xk * wb.z; aB.w += xk * wb.w;
    }
    ushort4 oa, ob;
    oa.x = f2bf(aA.x); oa.y = f2bf(aA.y); oa.z = f2bf(aA.z); oa.w = f2bf(aA.w);
    ob.x = f2bf(aB.x); ob.y = f2bf(aB.y); ob.z = f2bf(aB.z); ob.w = f2bf(aB.w);
    *(ushort4*)(A + (size_t)r * 64 + 4 * li) = oa;
    *(ushort4*)(B + (size_t)r * 64 + 4 * li) = ob;
}

// ------------- standalone A/B tables (fallback when ws too small) -------------
__global__ __launch_bounds__(256) void k_matmulAB(
    const float* __restrict__ h, const float* __restrict__ WA,
    const float* __restrict__ bA, const float* __restrict__ WB,
    ushort_t* __restrict__ A, ushort_t* __restrict__ B, int N)
{
    __shared__ float xs[16][68];
    const int row16 = threadIdx.x >> 4;
    const int li    = threadIdx.x & 15;
    const int r     = blockIdx.x * 16 + row16;
    if (r >= N) return;
    float4 x4 = *(const float4*)(h + (size_t)r * 64 + 4 * li);
    xs[row16][4*li+0] = x4.x; xs[row16][4*li+1] = x4.y;
    xs[row16][4*li+2] = x4.z; xs[row16][4*li+3] = x4.w;
    float4 accA = *(const float4*)(bA + 4 * li);
    float4 accB = make_float4(0.f, 0.f, 0.f, 0.f);
#pragma unroll
    for (int k = 0; k < 64; k++) {
        float xk = xs[row16][k];
        float4 wa = *(const float4*)(WA + k * 64 + 4 * li);
        float4 wb = *(const float4*)(WB + k * 64 + 4 * li);
        accA.x += xk * wa.x; accA.y += xk * wa.y;
        accA.z += xk * wa.z; accA.w += xk * wa.w;
        accB.x += xk * wb.x; accB.y += xk * wb.y;
        accB.z += xk * wb.z; accB.w += xk * wb.w;
    }
    ushort4 oa, ob;
    oa.x = f2bf(accA.x); oa.y = f2bf(accA.y); oa.z = f2bf(accA.z); oa.w = f2bf(accA.w);
    ob.x = f2bf(accB.x); ob.y = f2bf(accB.y); ob.z = f2bf(accB.z); ob.w = f2bf(accB.w);
    *(ushort4*)(A + (size_t)r * 64 + 4 * li) = oa;
    *(ushort4*)(B + (size_t)r * 64 + 4 * li) = ob;
}

// ------------- fused: head i score (+ GIN layer i) (+ next head A/B) ---------
// 16 lanes per dst node; streaming CSR entries {src,eid,ex,ey}; score in CSR order.
// MODE 0: score_csr = ; 1: score_csr += ; 2 (final): score_out[eid] = relu(score_csr + val)
template <int MODE, int HASGIN, int AGGBF, int EPI>
__global__ __launch_bounds__(256) void k_fused(
    const float* __restrict__ h, float* __restrict__ hout,
    const ushort_t* __restrict__ hbf, ushort_t* __restrict__ hbfout,
    const ushort_t* __restrict__ A, const ushort_t* __restrict__ Bm,
    const int4* __restrict__ entries, const int* __restrict__ offsets,
    float* __restrict__ score_csr, float* __restrict__ score_out,
    const float* __restrict__ Wc, const float* __restrict__ W2v,
    const float* __restrict__ b2p, const float* __restrict__ epsp,
    const float* __restrict__ W1, const float* __restrict__ b1,
    const float* __restrict__ s1, const float* __restrict__ sh1,
    const float* __restrict__ W2, const float* __restrict__ b2,
    const float* __restrict__ as_, const float* __restrict__ ash,
    const float* __restrict__ gs, const float* __restrict__ gsh,
    const float* __restrict__ WAn, const float* __restrict__ bAn,
    const float* __restrict__ WBn,
    ushort_t* __restrict__ Aout, ushort_t* __restrict__ Bout, int N)
{
    __shared__ float xs[16][68];
    __shared__ float ts[16][68];
    const int row16 = threadIdx.x >> 4;
    const int li    = threadIdx.x & 15;
    const int r     = blockIdx.x * 16 + row16;
    if (r >= N) return;

    const float4 wc0 = *(const float4*)(Wc + li*4);
    const float4 wc1 = *(const float4*)(Wc + 64 + li*4);
    const float4 w2v = *(const float4*)(W2v + li*4);
    const float bb2 = b2p[0];
    ushort4 bu = *(const ushort4*)(Bm + (size_t)r * 64 + li*4);
    const float4 brow = make_float4(bf2f(bu.x), bf2f(bu.y), bf2f(bu.z), bf2f(bu.w));

    const int beg = offsets[r], end = offsets[r + 1];
    float4 acc = make_float4(0.f, 0.f, 0.f, 0.f);

    int k = beg;
    for (; k + 3 < end; k += 4) {
        int4 e0 = entries[k], e1 = entries[k+1], e2 = entries[k+2], e3 = entries[k+3];
        ushort4 a0 = *(const ushort4*)(A + (size_t)e0.x * 64 + li*4);
        ushort4 a1 = *(const ushort4*)(A + (size_t)e1.x * 64 + li*4);
        ushort4 a2 = *(const ushort4*)(A + (size_t)e2.x * 64 + li*4);
        ushort4 a3 = *(const ushort4*)(A + (size_t)e3.x * 64 + li*4);
        if (HASGIN) {
            if (AGGBF) {
                ushort4 g0 = *(const ushort4*)(hbf + (size_t)e0.x * 64 + li*4);
                ushort4 g1 = *(const ushort4*)(hbf + (size_t)e1.x * 64 + li*4);
                ushort4 g2 = *(const ushort4*)(hbf + (size_t)e2.x * 64 + li*4);
                ushort4 g3 = *(const ushort4*)(hbf + (size_t)e3.x * 64 + li*4);
                acc.x += bf2f(g0.x) + bf2f(g1.x) + bf2f(g2.x) + bf2f(g3.x);
                acc.y += bf2f(g0.y) + bf2f(g1.y) + bf2f(g2.y) + bf2f(g3.y);
                acc.z += bf2f(g0.z) + bf2f(g1.z) + bf2f(g2.z) + bf2f(g3.z);
                acc.w += bf2f(g0.w) + bf2f(g1.w) + bf2f(g2.w) + bf2f(g3.w);
            } else {
                float4 g0 = *(const float4*)(h + (size_t)e0.x * 64 + li*4);
                float4 g1 = *(const float4*)(h + (size_t)e1.x * 64 + li*4);
                float4 g2 = *(const float4*)(h + (size_t)e2.x * 64 + li*4);
                float4 g3 = *(const float4*)(h + (size_t)e3.x * 64 + li*4);
                acc.x += g0.x + g1.x + g2.x + g3.x;
                acc.y += g0.y + g1.y + g2.y + g3.y;
                acc.z += g0.z + g1.z + g2.z + g3.z;
                acc.w += g0.w + g1.w + g2.w + g3.w;
            }
        }
        float p0 = edge_p(a0, brow, __int_as_float(e0.z), __int_as_float(e0.w), wc0, wc1, w2v);
        float p1 = edge_p(a1, brow, __int_as_float(e1.z), __int_as_float(e1.w), wc0, wc1, w2v);
        float p2 = edge_p(a2, brow, __int_as_float(e2.z), __int_as_float(e2.w), wc0, wc1, w2v);
        float p3 = edge_p(a3, brow, __int_as_float(e3.z), __int_as_float(e3.w), wc0, wc1, w2v);
        RED16(p0) RED16(p1) RED16(p2) RED16(p3)
        if (li == 0) {
            if (MODE == 0) {
                score_csr[k]   = p0 + bb2; score_csr[k+1] = p1 + bb2;
                score_csr[k+2] = p2 + bb2; score_csr[k+3] = p3 + bb2;
            } else if (MODE == 1) {
                score_csr[k]   += p0 + bb2; score_csr[k+1] += p1 + bb2;
                score_csr[k+2] += p2 + bb2; score_csr[k+3] += p3 + bb2;
            } else {
                score_out[e0.y] = fmaxf(score_csr[k]   + p0 + bb2, 0.f);
                score_out[e1.y] = fmaxf(score_csr[k+1] + p1 + bb2, 0.f);
                score_out[e2.y] = fmaxf(score_csr[k+2] + p2 + bb2, 0.f);
                score_out[e3.y] = fmaxf(score_csr[k+3] + p3 + bb2, 0.f);
            }
        }
    }
    for (; k < end; k++) {
        int4 e0 = entries[k];
        ushort4 a0 = *(const ushort4*)(A + (size_t)e0.x * 64 + li*4);
        if (HASGIN) {
            if (AGGBF) {
                ushort4 g0 = *(const ushort4*)(hbf + (size_t)e0.x * 64 + li*4);
                acc.x += bf2f(g0.x); acc.y += bf2f(g0.y);
                acc.z += bf2f(g0.z); acc.w += bf2f(g0.w);
            } else {
                float4 g0 = *(const float4*)(h + (size_t)e0.x * 64 + li*4);
                acc.x += g0.x; acc.y += g0.y; acc.z += g0.z; acc.w += g0.w;
            }
        }
        float p0 = edge_p(a0, brow, __int_as_float(e0.z), __int_as_float(e0.w), wc0, wc1, w2v);
        RED16(p0)
        if (li == 0) {
            if (MODE == 0)      score_csr[k] = p0 + bb2;
            else if (MODE == 1) score_csr[k] += p0 + bb2;
            else score_out[e0.y] = fmaxf(score_csr[k] + p0 + bb2, 0.f);
        }
    }

    if (!HASGIN) return;

    // --- GIN MLP + residual ---
    const float epsv = 1.0f + epsp[0];
    float4 hv = *(const float4*)(h + (size_t)r * 64 + 4 * li);
    xs[row16][4*li+0] = epsv * hv.x + acc.x;
    xs[row16][4*li+1] = epsv * hv.y + acc.y;
    xs[row16][4*li+2] = epsv * hv.z + acc.z;
    xs[row16][4*li+3] = epsv * hv.w + acc.w;

    float4 t = *(const float4*)(b1 + 4 * li);
#pragma unroll
    for (int kk = 0; kk < 64; kk++) {
        float xk = xs[row16][kk];
        float4 wv = *(const float4*)(W1 + kk * 64 + 4 * li);
        t.x += xk * wv.x; t.y += xk * wv.y; t.z += xk * wv.z; t.w += xk * wv.w;
    }
    {
        float4 sc = *(const float4*)(s1 + 4 * li);
        float4 sh = *(const float4*)(sh1 + 4 * li);
        t.x = fmaxf(t.x * sc.x + sh.x, 0.f);
        t.y = fmaxf(t.y * sc.y + sh.y, 0.f);
        t.z = fmaxf(t.z * sc.z + sh.z, 0.f);
        t.w = fmaxf(t.w * sc.w + sh.w, 0.f);
    }
    ts[row16][4*li+0] = t.x; ts[row16][4*li+1] = t.y;
    ts[row16][4*li+2] = t.z; ts[row16][4*li+3] = t.w;

    float4 u = *(const float4*)(b2 + 4 * li);
#pragma unroll
    for (int kk = 0; kk < 64; kk++) {
        float tk = ts[row16][kk];
        float4 wv = *(const float4*)(W2 + kk * 64 + 4 * li);
        u.x += tk * wv.x; u.y += tk * wv.y; u.z += tk * wv.z; u.w += tk * wv.w;
    }
    {
        float4 sc = *(const float4*)(as_ + 4 * li);
        float4 sh = *(const float4*)(ash + 4 * li);
        u.x = fmaxf(u.x * sc.x + sh.x, 0.f);
        u.y = fmaxf(u.y * sc.y + sh.y, 0.f);
        u.z = fmaxf(u.z * sc.z + sh.z, 0.f);
        u.w = fmaxf(u.w * sc.w + sh.w, 0.f);
        sc = *(const float4*)(gs + 4 * li);
        sh = *(const float4*)(gsh + 4 * li);
        u.x = fmaxf(u.x * sc.x + sh.x, 0.f);
        u.y = fmaxf(u.y * sc.y + sh.y, 0.f);
        u.z = fmaxf(u.z * sc.z + sh.z, 0.f);
        u.w = fmaxf(u.w * sc.w + sh.w, 0.f);
    }
    float4 o = make_float4(hv.x + u.x, hv.y + u.y, hv.z + u.z, hv.w + u.w);
    *(float4*)(hout + (size_t)r * 64 + 4 * li) = o;
    if (AGGBF) {
        ushort4 ob;
        ob.x = f2bf(o.x); ob.y = f2bf(o.y); ob.z = f2bf(o.z); ob.w = f2bf(o.w);
        *(ushort4*)(hbfout + (size_t)r * 64 + 4 * li) = ob;
    }

    if (EPI) {
        // next head's A/B from fresh o (same wave -> no barrier)
        xs[row16][4*li+0] = o.x; xs[row16][4*li+1] = o.y;
        xs[row16][4*li+2] = o.z; xs[row16][4*li+3] = o.w;
        float4 aA = *(const float4*)(bAn + 4 * li);
        float4 aB = make_float4(0.f, 0.f, 0.f, 0.f);
#pragma unroll
        for (int kk = 0; kk < 64; kk++) {
            float xk = xs[row16][kk];
            float4 wa = *(const float4*)(WAn + kk * 64 + 4 * li);
            float4 wb = *(const float4*)(WBn + kk * 64 + 4 * li);
            aA.x += xk * wa.x; aA.y += xk * wa.y; aA.z += xk * wa.z; aA.w += xk * wa.w;
            aB.x += xk * wb.x; aB.y += xk * wb.y; aB.z += xk * wb.z; aB.w += xk * wb.w;
        }
        ushort4 oa, ob;
        oa.x = f2bf(aA.x); oa.y = f2bf(aA.y); oa.z = f2bf(aA.z); oa.w = f2bf(aA.w);
        ob.x = f2bf(aB.x); ob.y = f2bf(aB.y); ob.z = f2bf(aB.z); ob.w = f2bf(aB.w);
        *(ushort4*)(Aout + (size_t)r * 64 + li*4) = oa;
        *(ushort4*)(Bout + (size_t)r * 64 + li*4) = ob;
    }
}

extern "C" void kernel_launch(void* const* d_in, const int* in_sizes, int n_in,
                              void* d_out, int out_size, void* d_ws, size_t ws_size,
                              hipStream_t stream) {
    const float* h_in  = (const float*)d_in[0];
    const float* e     = (const float*)d_in[1];
    const int*   src   = (const int*)d_in[2];
    const int*   dst   = (const int*)d_in[3];
    const float* emb_W = (const float*)d_in[4];
    const float* emb_b = (const float*)d_in[5];
    const float* eps   = (const float*)d_in[6];
    const float* mW1   = (const float*)d_in[7];
    const float* mb1   = (const float*)d_in[8];
    const float* mbs   = (const float*)d_in[9];
    const float* mbsh  = (const float*)d_in[10];
    const float* mW2   = (const float*)d_in[11];
    const float* mb2   = (const float*)d_in[12];
    const float* as_   = (const float*)d_in[13];
    const float* ash   = (const float*)d_in[14];
    const float* gs    = (const float*)d_in[15];
    const float* gsh   = (const float*)d_in[16];
    const float* pW1   = (const float*)d_in[17];
    const float* pb1   = (const float*)d_in[18];
    const float* pW2   = (const float*)d_in[19];
    const float* pb2   = (const float*)d_in[20];

    const int N  = in_sizes[0] / 64;
    const int E  = in_sizes[2];
    const int Lr = in_sizes[6];
    const size_t nrow = (size_t)N * 64;

    float* score = (float*)d_out;

    char* wp = (char*)d_ws;
    auto take = [&](size_t b) -> char* {
        char* p = wp; wp += (b + 255) & ~(size_t)255; return p;
    };
    float*    h0        = (float*)take(nrow * 4);
    float*    h1        = (float*)take(nrow * 4);
    ushort_t* A0        = (ushort_t*)take(nrow * 2);
    ushort_t* B0        = (ushort_t*)take(nrow * 2);
    int4*     entries   = (int4*)take((size_t)E * 16);
    float*    score_csr = (float*)take((size_t)E * 4);
    int*      offsets   = (int*)take((size_t)(N + 1) * 4);
    int*      cursor    = (int*)take((size_t)N * 4);
    int*      bsum      = (int*)take(1024);
    ushort_t* hbf0      = (ushort_t*)take(nrow * 2);
    ushort_t* hbf1      = (ushort_t*)take(nrow * 2);
    size_t need_bf = (size_t)(wp - (char*)d_ws);
    ushort_t* A1        = (ushort_t*)take(nrow * 2);
    ushort_t* B1        = (ushort_t*)take(nrow * 2);
    size_t need_epi = (size_t)(wp - (char*)d_ws);

    const bool use_bf  = ws_size >= need_bf;
    const bool use_epi = ws_size >= need_epi;
    if (!use_bf) { hbf0 = nullptr; hbf1 = nullptr; }

    const int rowBlocks = (N + 15) / 16;
    const int edgeGrid  = (E + 255) / 256;
    const int nb        = (N + 1023) / 1024;

    // ---- CSR build ----
    hipMemsetAsync(cursor, 0, (size_t)N * sizeof(int), stream);
    k_count<<<edgeGrid, 256, 0, stream>>>(dst, cursor, E);
    k_scanA<<<nb, 1024, 0, stream>>>(cursor, offsets, bsum, N);
    k_scanB<<<1, 256, 0, stream>>>(bsum, nb, offsets + N);
    k_scanC<<<(N + 255) / 256, 256, 0, stream>>>(offsets, bsum, cursor, N);
    k_fill<<<edgeGrid, 256, 0, stream>>>(src, dst, e, cursor, entries, E);

    // ---- embed + head-0 tables ----
    k_embed_ab<<<rowBlocks, 256, 0, stream>>>(
        h_in, emb_W, emb_b, h0, hbf0, pW1, pb1, pW1 + 64 * 64, A0, B0, N);

    float* hcur = h0;      float* hnext = h1;
    ushort_t* bcur = hbf0; ushort_t* bnext = hbf1;
    ushort_t* Acur = A0;   ushort_t* Bcur = B0;
    ushort_t* Aalt = use_epi ? A1 : A0;
    ushort_t* Balt = use_epi ? B1 : B0;

    for (int i = 0; i < Lr; i++) {
        const float* pw  = pW1 + (size_t)i * 130 * 64;
        const float* Wc  = pw + 128 * 64;
        const float* w2  = pW2 + (size_t)i * 64;
        const float* b2  = pb2 + i;
        const float* pwn = pW1 + (size_t)(i + 1) * 130 * 64;
        const float* gW1 = mW1 + (size_t)i * 64 * 64;
        const float* gW2 = mW2 + (size_t)i * 64 * 64;

        if (use_epi) {
            if (i == 0)
                k_fused<0,1,1,1><<<rowBlocks, 256, 0, stream>>>(
                    hcur, hnext, bcur, bnext, Acur, Bcur, entries, offsets,
                    score_csr, nullptr, Wc, w2, b2, eps + i,
                    gW1, mb1 + i*64, mbs + i*64, mbsh + i*64, gW2, mb2 + i*64,
                    as_ + i*64, ash + i*64, gs + i*64, gsh + i*64,
                    pwn, pb1 + (i+1)*64, pwn + 64*64, Aalt, Balt, N);
            else
                k_fused<1,1,1,1><<<rowBlocks, 256, 0, stream>>>(
                    hcur, hnext, bcur, bnext, Acur, Bcur, entries, offsets,
                    score_csr, nullptr, Wc, w2, b2, eps + i,
                    gW1, mb1 + i*64, mbs + i*64, mbsh + i*64, gW2, mb2 + i*64,
                    as_ + i*64, ash + i*64, gs + i*64, gsh + i*64,
                    pwn, pb1 + (i+1)*64, pwn + 64*64, Aalt, Balt, N);
            { ushort_t* t = Acur; Acur = Aalt; Aalt = t; }
            { ushort_t* t = Bcur; Bcur = Balt; Balt = t; }
        } else if (use_bf) {
            if (i == 0)
                k_fused<0,1,1,0><<<rowBlocks, 256, 0, stream>>>(
                    hcur, hnext, bcur, bnext, Acur, Bcur, entries, offsets,
                    score_csr, nullptr, Wc, w2, b2, eps + i,
                    gW1, mb1 + i*64, mbs + i*64, mbsh + i*64, gW2, mb2 + i*64,
                    as_ + i*64, ash + i*64, gs + i*64, gsh + i*64,
                    nullptr, nullptr, nullptr, nullptr, nullptr, N);
            else
                k_fused<1,1,1,0><<<rowBlocks, 256, 0, stream>>>(
                    hcur, hnext, bcur, bnext, Acur, Bcur, entries, offsets,
                    score_csr, nullptr, Wc, w2, b2, eps + i,
                    gW1, mb1 + i*64, mbs + i*64, mbsh + i*64, gW2, mb2 + i*64,
                    as_ + i*64, ash + i*64, gs + i*64, gsh + i*64,
                    nullptr, nullptr, nullptr, nullptr, nullptr, N);
            k_matmulAB<<<rowBlocks, 256, 0, stream>>>(
                hnext, pwn, pb1 + (i+1)*64, pwn + 64*64, A0, B0, N);
        } else {
            if (i == 0)
                k_fused<0,1,0,0><<<rowBlocks, 256, 0, stream>>>(
                    hcur, hnext, bcur, bnext, Acur, Bcur, entries, offsets,
                    score_csr, nullptr, Wc, w2, b2, eps + i,
                    gW1, mb1 + i*64, mbs + i*64, mbsh + i*64, gW2, mb2 + i*64,
                    as_ + i*64, ash + i*64, gs + i*64, gsh + i*64,
                    nullptr, nullptr, nullptr, nullptr, nullptr, N);
            else
                k_fused<1,1,0,0><<<rowBlocks, 256, 0, stream>>>(
                    hcur, hnext, bcur, bnext, Acur, Bcur, entries, offsets,
                    score_csr, nullptr, Wc, w2, b2, eps + i,
                    gW1, mb1 + i*64, mbs + i*64, mbsh + i*64, gW2, mb2 + i*64,
                    as_ + i*64, ash + i*64, gs + i*64, gsh + i*64,
                    nullptr, nullptr, nullptr, nullptr, nullptr, N);
            k_matmulAB<<<rowBlocks, 256, 0, stream>>>(
                hnext, pwn, pb1 + (i+1)*64, pwn + 64*64, A0, B0, N);
        }
        { float* t = hcur; hcur = hnext; hnext = t; }
        { ushort_t* t = bcur; bcur = bnext; bnext = t; }
    }

    // ---- final head: score_out[eid] = relu(score_csr + pred) ----
    {
        const float* pw = pW1 + (size_t)Lr * 130 * 64;
        const float* Wc = pw + 128 * 64;
        const float* w2 = pW2 + (size_t)Lr * 64;
        const float* b2 = pb2 + Lr;
        k_fused<2,0,0,0><<<rowBlocks, 256, 0, stream>>>(
            hcur, nullptr, nullptr, nullptr, Acur, Bcur, entries, offsets,
            score_csr, score, Wc, w2, b2, nullptr,
            nullptr, nullptr, nullptr, nullptr, nullptr, nullptr,
            nullptr, nullptr, nullptr, nullptr,
            nullptr, nullptr, nullptr, nullptr, nullptr, N);
    }
}